// Round 1
// baseline (120.361 us; speedup 1.0000x reference)
//
#include <hip/hip_runtime.h>
#include <hip/hip_bf16.h>

// Per-token head-mixing attention, MI355X (gfx950).
// One wave (64 lanes) per token; tokens = B*S = 32768; 16 heads x 64 dim.
//
// Phase 1: logits^T = K * Q^T  via mfma_f32_16x16x32_bf16 (A=K rows, B=Q rows),
//          Q,K split into bf16 hi+lo (3 MFMAs per 32-d chunk) for ~fp32 logits.
// Phase 2: wave-parallel softmax over the 16 key-heads (lane-local 4 + xor16/32).
// Phase 3: out = W * V, W-frag assembled in-register (4 shfl), V read from
//          global directly in B-frag pattern. K-dim padded 16->32 with zeros.
// No LDS, no barriers; all global accesses touch each byte exactly once.

typedef __attribute__((ext_vector_type(8))) short bf16x8;
typedef __attribute__((ext_vector_type(4))) float f32x4;

__device__ __forceinline__ unsigned short f2bf(float x) {
    unsigned int b = __float_as_uint(x);
    b += 0x7fffu + ((b >> 16) & 1u);   // round-to-nearest-even
    return (unsigned short)(b >> 16);
}
__device__ __forceinline__ float bf2f(unsigned short u) {
    return __uint_as_float(((unsigned int)u) << 16);
}

__global__ void __launch_bounds__(256)
headmix_attn_kernel(const float* __restrict__ Q, const float* __restrict__ K,
                    const float* __restrict__ V, float* __restrict__ O, int ntok)
{
    const int lane = (int)(threadIdx.x & 63u);
    const int wv   = (int)(threadIdx.x >> 6);
    const int tok  = (int)blockIdx.x * 4 + wv;
    if (tok >= ntok) return;

    const int r = lane & 15;   // A row (j) / B col (h) index
    const int g = lane >> 4;   // k-group 0..3

    const size_t base = (size_t)tok * 1024;
    const float* qt = Q + base;
    const float* kt = K + base;
    const float* vt = V + base;
    float*       ot = O + base;

    // ---------------- Phase 1: logits^T[j][h] = sum_d K[j][d] * (Q[h][d]/8) ---
    f32x4 acc = {0.f, 0.f, 0.f, 0.f};
#pragma unroll
    for (int mi = 0; mi < 2; ++mi) {
        const int off = r * 64 + mi * 32 + g * 8;   // 8 contiguous d's per lane
        f32x4 kv0 = *(const f32x4*)(kt + off);
        f32x4 kv1 = *(const f32x4*)(kt + off + 4);
        f32x4 qv0 = *(const f32x4*)(qt + off);
        f32x4 qv1 = *(const f32x4*)(qt + off + 4);

        float kf[8], qf[8];
#pragma unroll
        for (int i = 0; i < 4; ++i) {
            kf[i]     = kv0[i];
            kf[i + 4] = kv1[i];
            qf[i]     = qv0[i] * 0.125f;   // fold 1/sqrt(64) into Q (exact pow2)
            qf[i + 4] = qv1[i] * 0.125f;
        }

        bf16x8 kh, kl, qh, ql;
#pragma unroll
        for (int i = 0; i < 8; ++i) {
            unsigned short khi = f2bf(kf[i]);
            unsigned short qhi = f2bf(qf[i]);
            kh[i] = (short)khi;
            qh[i] = (short)qhi;
            kl[i] = (short)f2bf(kf[i] - bf2f(khi));   // lo residual
            ql[i] = (short)f2bf(qf[i] - bf2f(qhi));
        }
        // (kh+kl)*(qh+ql) ~= kh*qh + kl*qh + kh*ql  (ql*kl ~ 2^-18, dropped)
        acc = __builtin_amdgcn_mfma_f32_16x16x32_bf16(kh, qh, acc, 0, 0, 0);
        acc = __builtin_amdgcn_mfma_f32_16x16x32_bf16(kl, qh, acc, 0, 0, 0);
        acc = __builtin_amdgcn_mfma_f32_16x16x32_bf16(kh, ql, acc, 0, 0, 0);
    }
    // D layout: col = h = lane&15, rows j = 4g + i  (m89-verified mapping)

    // ---------------- Phase 2: softmax over j (16) for column h=r ------------
    float m = fmaxf(fmaxf(acc[0], acc[1]), fmaxf(acc[2], acc[3]));
    m = fmaxf(m, __shfl_xor(m, 16));
    m = fmaxf(m, __shfl_xor(m, 32));
    float p0 = __expf(acc[0] - m);
    float p1 = __expf(acc[1] - m);
    float p2 = __expf(acc[2] - m);
    float p3 = __expf(acc[3] - m);
    float s = p0 + p1 + p2 + p3;
    s += __shfl_xor(s, 16);
    s += __shfl_xor(s, 32);
    const float inv = 1.0f / s;
    p0 *= inv; p1 *= inv; p2 *= inv; p3 *= inv;

    // lane holds W[h=r][j=4g+i]; pack to bf16 pairs
    unsigned int w01 = (unsigned int)f2bf(p0) | ((unsigned int)f2bf(p1) << 16);
    unsigned int w23 = (unsigned int)f2bf(p2) | ((unsigned int)f2bf(p3) << 16);

    // ---------------- Phase 3: out = W (16x32, j-padded) * V (32x64) ---------
    // A-frag needs lane: row h=r, k-elems j = 8g..8g+7 -> gather from lane
    // groups 2g and 2g+1 (same col r). g>=2 => j>=16 => zero padding.
    const int src0 = (r + 32 * g) & 63;
    const int src1 = (r + 32 * g + 16) & 63;
    unsigned int a0 = (unsigned int)__shfl((int)w01, src0);
    unsigned int a1 = (unsigned int)__shfl((int)w23, src0);
    unsigned int a2 = (unsigned int)__shfl((int)w01, src1);
    unsigned int a3 = (unsigned int)__shfl((int)w23, src1);
    if (g >= 2) { a0 = 0u; a1 = 0u; a2 = 0u; a3 = 0u; }

    union { bf16x8 v; unsigned int u[4]; } wf;
    wf.u[0] = a0; wf.u[1] = a1; wf.u[2] = a2; wf.u[3] = a3;

    const f32x4 zero = {0.f, 0.f, 0.f, 0.f};
#pragma unroll
    for (int dt = 0; dt < 4; ++dt) {
        // B-frag: lane: col = d-in-tile = r, k-elems j = 8g+i; zero for g>=2
        union { bf16x8 v; unsigned int u[4]; } vf;
        vf.u[0] = 0u; vf.u[1] = 0u; vf.u[2] = 0u; vf.u[3] = 0u;
        if (g < 2) {
            const float* vp = vt + (8 * g) * 64 + dt * 16 + r;
#pragma unroll
            for (int i = 0; i < 4; ++i) {
                float v0 = vp[(2 * i) * 64];
                float v1 = vp[(2 * i + 1) * 64];
                vf.u[i] = (unsigned int)f2bf(v0) | ((unsigned int)f2bf(v1) << 16);
            }
        }
        f32x4 o = __builtin_amdgcn_mfma_f32_16x16x32_bf16(wf.v, vf.v, zero, 0, 0, 0);
        // D: row = h = 4g+i, col = d = dt*16 + r
        float* op = ot + (4 * g) * 64 + dt * 16 + r;
#pragma unroll
        for (int i = 0; i < 4; ++i) op[i * 64] = o[i];
    }
}

extern "C" void kernel_launch(void* const* d_in, const int* in_sizes, int n_in,
                              void* d_out, int out_size, void* d_ws, size_t ws_size,
                              hipStream_t stream) {
    const float* q = (const float*)d_in[0];
    const float* k = (const float*)d_in[1];
    const float* v = (const float*)d_in[2];
    float* o = (float*)d_out;
    const int ntok = in_sizes[0] / 1024;          // B*S = 32768
    const int blocks = (ntok + 3) / 4;            // 4 tokens (waves) per block
    hipLaunchKernelGGL(headmix_attn_kernel, dim3(blocks), dim3(256), 0, stream,
                       q, k, v, o, ntok);
}

// Round 2
// 100.636 us; speedup vs baseline: 1.1960x; 1.1960x over previous
//
#include <hip/hip_runtime.h>
#include <hip/hip_bf16.h>

// Per-token head-mixing attention, MI355X (gfx950).
// One wave (64 lanes) per token; tokens = B*S = 32768; 16 heads x 64 dim.
//
// R2 change: ALL global loads (Q, K, V) are issued at the top of the wave
// before any compute — one memory-latency exposure per wave instead of ~4
// serially-dependent ones. V loads run on all 64 lanes (g>=2 duplicates
// g&1's addresses; same-address lanes dedup in cache, no extra HBM traffic).
//
// Phase 1: logits^T = K * Q^T via mfma_f32_16x16x32_bf16, Q/K split into
//          bf16 hi+lo (3 MFMAs per 32-d chunk) for ~fp32-accurate logits.
// Phase 2: wave-parallel softmax over 16 key-heads (lane-local 4 + xor16/32),
//          1/sqrt(64) folded into the exp argument.
// Phase 3: out = W (16x32, j-padded) * V (32x64) via MFMA; W-frag assembled
//          in-register with 4 shfls. No LDS, no barriers.

typedef __attribute__((ext_vector_type(8))) short bf16x8;
typedef __attribute__((ext_vector_type(4))) float f32x4;

__device__ __forceinline__ unsigned short f2bf(float x) {
    unsigned int b = __float_as_uint(x);
    b += 0x7fffu + ((b >> 16) & 1u);   // round-to-nearest-even
    return (unsigned short)(b >> 16);
}
__device__ __forceinline__ float bf2f(unsigned short u) {
    return __uint_as_float(((unsigned int)u) << 16);
}

__global__ void __launch_bounds__(256)
headmix_attn_kernel(const float* __restrict__ Q, const float* __restrict__ K,
                    const float* __restrict__ V, float* __restrict__ O, int ntok)
{
    const int lane = (int)(threadIdx.x & 63u);
    const int wv   = (int)(threadIdx.x >> 6);
    const int tok  = (int)blockIdx.x * 4 + wv;
    if (tok >= ntok) return;

    const int r = lane & 15;   // A row (j) / B col (h) index
    const int g = lane >> 4;   // k-group 0..3

    const size_t base = (size_t)tok * 1024;
    const float* qt = Q + base;
    const float* kt = K + base;
    const float* vt = V + base;
    float*       ot = O + base;

    // =================== issue ALL global loads up front =====================
    f32x4 kvv[2][2], qvv[2][2];
#pragma unroll
    for (int mi = 0; mi < 2; ++mi) {
        const int off = r * 64 + mi * 32 + g * 8;   // 8 contiguous d's per lane
        kvv[mi][0] = *(const f32x4*)(kt + off);
        kvv[mi][1] = *(const f32x4*)(kt + off + 4);
        qvv[mi][0] = *(const f32x4*)(qt + off);
        qvv[mi][1] = *(const f32x4*)(qt + off + 4);
    }
    // V in B-frag pattern: lane needs V[8g'+i][dt*16+r] for g'=g&1 (g>=2 lanes
    // duplicate g&1's addresses -> dedup'd in cache; their frag is zeroed later)
    float vraw[4][8];
#pragma unroll
    for (int dt = 0; dt < 4; ++dt) {
        const float* vp = vt + (8 * (g & 1)) * 64 + dt * 16 + r;
#pragma unroll
        for (int i = 0; i < 8; ++i)
            vraw[dt][i] = vp[i * 64];
    }

    // ---------------- Phase 1: logits^T[j][h] = sum_d K[j][d] * Q[h][d] ------
    f32x4 acc = {0.f, 0.f, 0.f, 0.f};
#pragma unroll
    for (int mi = 0; mi < 2; ++mi) {
        bf16x8 kh, kl, qh, ql;
#pragma unroll
        for (int half = 0; half < 2; ++half) {
#pragma unroll
            for (int i = 0; i < 4; ++i) {
                float kf = kvv[mi][half][i];
                float qf = qvv[mi][half][i];
                unsigned short khi = f2bf(kf);
                unsigned short qhi = f2bf(qf);
                kh[half * 4 + i] = (short)khi;
                qh[half * 4 + i] = (short)qhi;
                kl[half * 4 + i] = (short)f2bf(kf - bf2f(khi));
                ql[half * 4 + i] = (short)f2bf(qf - bf2f(qhi));
            }
        }
        // (kh+kl)*(qh+ql) ~= kh*qh + kl*qh + kh*ql  (kl*ql ~ 2^-18, dropped)
        acc = __builtin_amdgcn_mfma_f32_16x16x32_bf16(kh, qh, acc, 0, 0, 0);
        acc = __builtin_amdgcn_mfma_f32_16x16x32_bf16(kl, qh, acc, 0, 0, 0);
        acc = __builtin_amdgcn_mfma_f32_16x16x32_bf16(kh, ql, acc, 0, 0, 0);
    }
    // D layout: col = h = lane&15, rows j = 4g + i

    // ---------------- Phase 2: softmax over j (16) for column h=r ------------
    // 1/sqrt(64) = 0.125 folded into the exp argument (exact pow2 scale).
    float m = fmaxf(fmaxf(acc[0], acc[1]), fmaxf(acc[2], acc[3]));
    m = fmaxf(m, __shfl_xor(m, 16));
    m = fmaxf(m, __shfl_xor(m, 32));
    float p0 = __expf(0.125f * (acc[0] - m));
    float p1 = __expf(0.125f * (acc[1] - m));
    float p2 = __expf(0.125f * (acc[2] - m));
    float p3 = __expf(0.125f * (acc[3] - m));
    float s = p0 + p1 + p2 + p3;
    s += __shfl_xor(s, 16);
    s += __shfl_xor(s, 32);
    const float inv = 1.0f / s;
    p0 *= inv; p1 *= inv; p2 *= inv; p3 *= inv;

    // lane holds W[h=r][j=4g+i]; pack to bf16 pairs
    unsigned int w01 = (unsigned int)f2bf(p0) | ((unsigned int)f2bf(p1) << 16);
    unsigned int w23 = (unsigned int)f2bf(p2) | ((unsigned int)f2bf(p3) << 16);

    // ---------------- Phase 3: out = W (16x32, j-padded) * V (32x64) ---------
    // A-frag: lane row h=r, k-elems j = 8g..8g+7 -> gather from lane groups
    // 2g and 2g+1 (same col r). g>=2 => j>=16 => zero padding.
    const int src0 = (r + 32 * g) & 63;
    const int src1 = (r + 32 * g + 16) & 63;
    unsigned int a0 = (unsigned int)__shfl((int)w01, src0);
    unsigned int a1 = (unsigned int)__shfl((int)w23, src0);
    unsigned int a2 = (unsigned int)__shfl((int)w01, src1);
    unsigned int a3 = (unsigned int)__shfl((int)w23, src1);
    if (g >= 2) { a0 = 0u; a1 = 0u; a2 = 0u; a3 = 0u; }

    union { bf16x8 v; unsigned int u[4]; } wf;
    wf.u[0] = a0; wf.u[1] = a1; wf.u[2] = a2; wf.u[3] = a3;

    const f32x4 zero = {0.f, 0.f, 0.f, 0.f};
#pragma unroll
    for (int dt = 0; dt < 4; ++dt) {
        union { bf16x8 v; unsigned int u[4]; } vf;
#pragma unroll
        for (int i = 0; i < 4; ++i) {
            unsigned int lo = (unsigned int)f2bf(vraw[dt][2 * i]);
            unsigned int hi = (unsigned int)f2bf(vraw[dt][2 * i + 1]);
            vf.u[i] = (g < 2) ? (lo | (hi << 16)) : 0u;
        }
        f32x4 o = __builtin_amdgcn_mfma_f32_16x16x32_bf16(wf.v, vf.v, zero, 0, 0, 0);
        // D: row = h = 4g+i, col = d = dt*16 + r
        float* op = ot + (4 * g) * 64 + dt * 16 + r;
#pragma unroll
        for (int i = 0; i < 4; ++i) op[i * 64] = o[i];
    }
}

extern "C" void kernel_launch(void* const* d_in, const int* in_sizes, int n_in,
                              void* d_out, int out_size, void* d_ws, size_t ws_size,
                              hipStream_t stream) {
    const float* q = (const float*)d_in[0];
    const float* k = (const float*)d_in[1];
    const float* v = (const float*)d_in[2];
    float* o = (float*)d_out;
    const int ntok = in_sizes[0] / 1024;          // B*S = 32768
    const int blocks = (ntok + 3) / 4;            // 4 tokens (waves) per block
    hipLaunchKernelGGL(headmix_attn_kernel, dim3(blocks), dim3(256), 0, stream,
                       q, k, v, o, ntok);
}

// Round 3
// 97.234 us; speedup vs baseline: 1.2379x; 1.0350x over previous
//
#include <hip/hip_runtime.h>
#include <hip/hip_bf16.h>

// Per-token head-mixing attention, MI355X (gfx950).
// One wave (64 lanes) per token; tokens = B*S = 32768; 16 heads x 64 dim.
//
// R3 change: force the "issue ALL loads before ANY compute" schedule that the
// R2 source asked for but the compiler undid (VGPR_Count stayed 36 -> loads
// were re-sunk for occupancy). Two levers:
//   1. __launch_bounds__(256, 4): permit ~128 VGPRs so regalloc can hold all
//      load results (20 waves/CU at ~100 VGPR is still ample TLP).
//   2. __builtin_amdgcn_sched_barrier(0) after the load block: scheduler may
//      not move any instruction across it, pinning loads above compute.
// Goal: ~16 KB in flight per wave, one memory-latency exposure per wave.
//
// Phase 1: logits^T = K * Q^T via mfma_f32_16x16x32_bf16, Q/K split into
//          bf16 hi+lo (3 MFMAs per 32-d chunk) for ~fp32-accurate logits.
// Phase 2: wave-parallel softmax over 16 key-heads (lane-local 4 + xor16/32).
// Phase 3: out = W (16x32, j-padded) * V (32x64) via MFMA; W-frag assembled
//          in-register with 4 shfls. No LDS, no barriers.

typedef __attribute__((ext_vector_type(8))) short bf16x8;
typedef __attribute__((ext_vector_type(4))) float f32x4;

__device__ __forceinline__ unsigned short f2bf(float x) {
    unsigned int b = __float_as_uint(x);
    b += 0x7fffu + ((b >> 16) & 1u);   // round-to-nearest-even
    return (unsigned short)(b >> 16);
}
__device__ __forceinline__ float bf2f(unsigned short u) {
    return __uint_as_float(((unsigned int)u) << 16);
}

__global__ void __launch_bounds__(256, 4)
headmix_attn_kernel(const float* __restrict__ Q, const float* __restrict__ K,
                    const float* __restrict__ V, float* __restrict__ O, int ntok)
{
    const int lane = (int)(threadIdx.x & 63u);
    const int wv   = (int)(threadIdx.x >> 6);
    const int tok  = (int)blockIdx.x * 4 + wv;
    if (tok >= ntok) return;

    const int r = lane & 15;   // A row (j) / B col (h) index
    const int g = lane >> 4;   // k-group 0..3

    const size_t base = (size_t)tok * 1024;
    const float* qt = Q + base;
    const float* kt = K + base;
    const float* vt = V + base;
    float*       ot = O + base;

    // =================== issue ALL global loads up front =====================
    f32x4 kvv[2][2], qvv[2][2];
#pragma unroll
    for (int mi = 0; mi < 2; ++mi) {
        const int off = r * 64 + mi * 32 + g * 8;   // 8 contiguous d's per lane
        kvv[mi][0] = *(const f32x4*)(kt + off);
        kvv[mi][1] = *(const f32x4*)(kt + off + 4);
        qvv[mi][0] = *(const f32x4*)(qt + off);
        qvv[mi][1] = *(const f32x4*)(qt + off + 4);
    }
    // V in B-frag pattern: lane needs V[8g'+i][dt*16+r] for g'=g&1 (g>=2 lanes
    // duplicate g&1's addresses -> dedup'd in cache; their frag is zeroed later)
    float vraw[4][8];
#pragma unroll
    for (int dt = 0; dt < 4; ++dt) {
        const float* vp = vt + (8 * (g & 1)) * 64 + dt * 16 + r;
#pragma unroll
        for (int i = 0; i < 8; ++i)
            vraw[dt][i] = vp[i * 64];
    }

    // Pin the schedule: nothing below may be hoisted above, loads may not sink.
    __builtin_amdgcn_sched_barrier(0);

    // ---------------- Phase 1: logits^T[j][h] = sum_d K[j][d] * Q[h][d] ------
    f32x4 acc = {0.f, 0.f, 0.f, 0.f};
#pragma unroll
    for (int mi = 0; mi < 2; ++mi) {
        bf16x8 kh, kl, qh, ql;
#pragma unroll
        for (int half = 0; half < 2; ++half) {
#pragma unroll
            for (int i = 0; i < 4; ++i) {
                float kf = kvv[mi][half][i];
                float qf = qvv[mi][half][i];
                unsigned short khi = f2bf(kf);
                unsigned short qhi = f2bf(qf);
                kh[half * 4 + i] = (short)khi;
                qh[half * 4 + i] = (short)qhi;
                kl[half * 4 + i] = (short)f2bf(kf - bf2f(khi));
                ql[half * 4 + i] = (short)f2bf(qf - bf2f(qhi));
            }
        }
        // (kh+kl)*(qh+ql) ~= kh*qh + kl*qh + kh*ql  (kl*ql ~ 2^-18, dropped)
        acc = __builtin_amdgcn_mfma_f32_16x16x32_bf16(kh, qh, acc, 0, 0, 0);
        acc = __builtin_amdgcn_mfma_f32_16x16x32_bf16(kl, qh, acc, 0, 0, 0);
        acc = __builtin_amdgcn_mfma_f32_16x16x32_bf16(kh, ql, acc, 0, 0, 0);
    }
    // D layout: col = h = lane&15, rows j = 4g + i

    // ---------------- Phase 2: softmax over j (16) for column h=r ------------
    // 1/sqrt(64) = 0.125 folded into the exp argument (exact pow2 scale).
    float m = fmaxf(fmaxf(acc[0], acc[1]), fmaxf(acc[2], acc[3]));
    m = fmaxf(m, __shfl_xor(m, 16));
    m = fmaxf(m, __shfl_xor(m, 32));
    float p0 = __expf(0.125f * (acc[0] - m));
    float p1 = __expf(0.125f * (acc[1] - m));
    float p2 = __expf(0.125f * (acc[2] - m));
    float p3 = __expf(0.125f * (acc[3] - m));
    float s = p0 + p1 + p2 + p3;
    s += __shfl_xor(s, 16);
    s += __shfl_xor(s, 32);
    const float inv = 1.0f / s;
    p0 *= inv; p1 *= inv; p2 *= inv; p3 *= inv;

    // lane holds W[h=r][j=4g+i]; pack to bf16 pairs
    unsigned int w01 = (unsigned int)f2bf(p0) | ((unsigned int)f2bf(p1) << 16);
    unsigned int w23 = (unsigned int)f2bf(p2) | ((unsigned int)f2bf(p3) << 16);

    // ---------------- Phase 3: out = W (16x32, j-padded) * V (32x64) ---------
    // A-frag: lane row h=r, k-elems j = 8g..8g+7 -> gather from lane groups
    // 2g and 2g+1 (same col r). g>=2 => j>=16 => zero padding.
    const int src0 = (r + 32 * g) & 63;
    const int src1 = (r + 32 * g + 16) & 63;
    unsigned int a0 = (unsigned int)__shfl((int)w01, src0);
    unsigned int a1 = (unsigned int)__shfl((int)w23, src0);
    unsigned int a2 = (unsigned int)__shfl((int)w01, src1);
    unsigned int a3 = (unsigned int)__shfl((int)w23, src1);
    if (g >= 2) { a0 = 0u; a1 = 0u; a2 = 0u; a3 = 0u; }

    union { bf16x8 v; unsigned int u[4]; } wf;
    wf.u[0] = a0; wf.u[1] = a1; wf.u[2] = a2; wf.u[3] = a3;

    const f32x4 zero = {0.f, 0.f, 0.f, 0.f};
#pragma unroll
    for (int dt = 0; dt < 4; ++dt) {
        union { bf16x8 v; unsigned int u[4]; } vf;
#pragma unroll
        for (int i = 0; i < 4; ++i) {
            unsigned int lo = (unsigned int)f2bf(vraw[dt][2 * i]);
            unsigned int hi = (unsigned int)f2bf(vraw[dt][2 * i + 1]);
            vf.u[i] = (g < 2) ? (lo | (hi << 16)) : 0u;
        }
        f32x4 o = __builtin_amdgcn_mfma_f32_16x16x32_bf16(wf.v, vf.v, zero, 0, 0, 0);
        // D: row = h = 4g+i, col = d = dt*16 + r
        float* op = ot + (4 * g) * 64 + dt * 16 + r;
#pragma unroll
        for (int i = 0; i < 4; ++i) op[i * 64] = o[i];
    }
}

extern "C" void kernel_launch(void* const* d_in, const int* in_sizes, int n_in,
                              void* d_out, int out_size, void* d_ws, size_t ws_size,
                              hipStream_t stream) {
    const float* q = (const float*)d_in[0];
    const float* k = (const float*)d_in[1];
    const float* v = (const float*)d_in[2];
    float* o = (float*)d_out;
    const int ntok = in_sizes[0] / 1024;          // B*S = 32768
    const int blocks = (ntok + 3) / 4;            // 4 tokens (waves) per block
    hipLaunchKernelGGL(headmix_attn_kernel, dim3(blocks), dim3(256), 0, stream,
                       q, k, v, o, ntok);
}